// Round 2
// baseline (6667.361 us; speedup 1.0000x reference)
//
#include <hip/hip_runtime.h>
#include <hip/hip_bf16.h>

// ---------------------------------------------------------------------------
// All reference tensors are float32 (setup_inputs uses jnp.float32 throughout),
// so every pointer here is float. Output = [y (2048) | hT (2*1024*32)] fp32.
// ---------------------------------------------------------------------------

// ---------------------------------------------------------------------------
// Kernel 1: per-graph fused  KNN -> EdgeConv MLP -> agg(max/mean/sum) -> nn1
//           -> nn2 -> segment max/min/sum/mean -> g[2048][256] (fp32, relu'd)
// One block per graph (128 nodes), 256 threads.
// ---------------------------------------------------------------------------
__global__ __launch_bounds__(256) void k_graph(
    const float* __restrict__ x,      // [N,5]
    const float* __restrict__ W1,     // [10,64]
    const float* __restrict__ b1,     // [64]
    const float* __restrict__ W2,     // [64,128]
    const float* __restrict__ b2,     // [128]
    const float* __restrict__ nn1W,   // [384,94]
    const float* __restrict__ nn1b,   // [94]
    const float* __restrict__ nn2W,   // [94,64]
    const float* __restrict__ nn2b,   // [64]
    float* __restrict__ g_out)        // [2048,256]
{
    __shared__ float xs[128][5];
    __shared__ int   nbr[128][4];
    __shared__ float sW1[10][64];
    __shared__ float sb1[64];
    __shared__ float sW2[64][128];
    __shared__ float sb2[128];
    __shared__ float agg_max[64][128];
    __shared__ float agg_sum[64][128];
    __shared__ float nnh[64][96];
    __shared__ float htile[64][64];
    __shared__ float gmax[64], gmin[64], gsum[64];

    const int tid = threadIdx.x;
    const int graph = blockIdx.x;
    const long base = (long)graph * 128;

    for (int i = tid; i < 128 * 5; i += 256) xs[i / 5][i % 5] = x[base * 5 + i];
    for (int i = tid; i < 640; i += 256) sW1[i >> 6][i & 63] = W1[i];
    if (tid < 64) sb1[tid] = b1[tid];
    for (int i = tid; i < 8192; i += 256) sW2[i >> 7][i & 127] = W2[i];
    if (tid < 128) sb2[tid] = b2[tid];
    if (tid >= 128 && tid < 192) {
        gmax[tid - 128] = -3.0e38f; gmin[tid - 128] = 3.0e38f; gsum[tid - 128] = 0.0f;
    }
    __syncthreads();

    // ---- KNN (k=4, loop=False), strict < keeps earlier index on ties (top_k stable)
    if (tid < 128) {
        const int n = tid;
        const float px = xs[n][0], py = xs[n][1], pz = xs[n][2];
        float bd[4] = {3e38f, 3e38f, 3e38f, 3e38f};
        int   bi[4] = {0, 0, 0, 0};
        for (int m = 0; m < 128; ++m) {
            if (m == n) continue;
            float dx = xs[m][0] - px, dy = xs[m][1] - py, dz = xs[m][2] - pz;
            // no-FMA-contraction fp32, same eval tree as numpy: (x*x + y*y) + z*z
            float d2 = __fadd_rn(__fadd_rn(__fmul_rn(dx, dx), __fmul_rn(dy, dy)),
                                 __fmul_rn(dz, dz));
            if (d2 < bd[3]) {
                int k = 3;
                while (k > 0 && d2 < bd[k - 1]) { bd[k] = bd[k - 1]; bi[k] = bi[k - 1]; --k; }
                bd[k] = d2; bi[k] = m;
            }
        }
        for (int k = 0; k < 4; ++k) nbr[n][k] = bi[k];
    }
    __syncthreads();

    for (int tb = 0; tb < 128; tb += 64) {
        for (int i = tid; i < 64 * 128; i += 256) {
            ((float*)agg_max)[i] = 0.0f;
            ((float*)agg_sum)[i] = 0.0f;
        }
        __syncthreads();

        // ---- EdgeConv messages: 64 nodes x 4 edges, one thread per edge
        {
            const int nt = tid >> 2;         // node within tile
            const int n  = tb + nt;          // node within graph
            const int k  = tid & 3;
            const int j  = nbr[n][k];        // neighbor (local)
            float f[10];
            #pragma unroll
            for (int d = 0; d < 5; ++d) { f[d] = xs[n][d]; f[5 + d] = xs[j][d] - xs[n][d]; }
            float h1[64];
            #pragma unroll
            for (int c = 0; c < 64; ++c) {
                float acc = sb1[c];
                #pragma unroll
                for (int d = 0; d < 10; ++d) acc += f[d] * sW1[d][c];
                h1[c] = fmaxf(acc, 0.0f);
            }
            for (int ch = 0; ch < 128; ++ch) {
                float acc = sb2[ch];
                #pragma unroll
                for (int c = 0; c < 64; ++c) acc += h1[c] * sW2[c][ch];
                float m = fmaxf(acc, 0.0f);   // m >= 0
                atomicAdd(&agg_sum[nt][ch], m);
                atomicMax((int*)&agg_max[nt][ch], __float_as_int(m)); // valid for >=0
            }
        }
        __syncthreads();

        // ---- nn1: [max|mean|sum] (384) -> 94, relu   (relu on 384-vec is no-op: all >=0)
        for (int o = tid; o < 64 * 94; o += 256) {
            const int node = o / 94;
            const int jj = o - node * 94;
            const float* wp = nn1W + jj;
            float acc = nn1b[jj];
            for (int c = 0; c < 128; ++c)
                acc += agg_max[node][c] * wp[(size_t)c * 94];
            for (int c = 0; c < 128; ++c)
                acc += (agg_sum[node][c] * 0.25f) * wp[(size_t)(128 + c) * 94];
            for (int c = 0; c < 128; ++c)
                acc += agg_sum[node][c] * wp[(size_t)(256 + c) * 94];
            nnh[node][jj] = fmaxf(acc, 0.0f);
        }
        __syncthreads();

        // ---- nn2: 94 -> 64 (no relu)
        for (int o = tid; o < 64 * 64; o += 256) {
            const int node = o >> 6;
            const int ch = o & 63;
            float acc = nn2b[ch];
            for (int c = 0; c < 94; ++c)
                acc += nnh[node][c] * nn2W[c * 64 + ch];
            htile[node][ch] = acc;
        }
        __syncthreads();

        // ---- fold tile into per-graph accumulators
        if (tid < 64) {
            const int ch = tid;
            float mx = gmax[ch], mn = gmin[ch], sm = gsum[ch];
            for (int n2 = 0; n2 < 64; ++n2) {
                float v = htile[n2][ch];
                mx = fmaxf(mx, v); mn = fminf(mn, v); sm += v;
            }
            gmax[ch] = mx; gmin[ch] = mn; gsum[ch] = sm;
        }
        __syncthreads();
    }

    if (tid < 64) {
        const int ch = tid;
        float* gp = g_out + (size_t)graph * 256;
        gp[ch]        = fmaxf(gmax[ch], 0.0f);
        gp[64 + ch]   = fmaxf(gmin[ch], 0.0f);
        gp[128 + ch]  = fmaxf(gsum[ch], 0.0f);
        gp[192 + ch]  = fmaxf(gsum[ch] * (1.0f / 128.0f), 0.0f);
    }
}

// ---------------------------------------------------------------------------
// Kernel 2: 2-layer GRU, T=2, B=1024, H=32, input 256 (with torch reshape
// scramble seq[t,b,c] = g[t*1024 + 4c + (b>>8)][b&255]).
// 128 threads = 4 batch elems x 32 hidden units.
// ---------------------------------------------------------------------------
__global__ __launch_bounds__(128) void k_gru(
    const float* __restrict__ g,      // [2048,256]
    const float* __restrict__ h1_in,  // [2,1024,32]
    const float* __restrict__ wih0, const float* __restrict__ whh0,
    const float* __restrict__ bih0, const float* __restrict__ bhh0,
    const float* __restrict__ wih1, const float* __restrict__ whh1,
    const float* __restrict__ bih1, const float* __restrict__ bhh1,
    float* __restrict__ out1,         // [2,1024,32]
    float* __restrict__ hT)           // -> d_out + 2048, [2,1024,32]
{
    __shared__ float xt[4][256];
    __shared__ float h0[4][32];
    __shared__ float h1l[4][32];
    const int tid = threadIdx.x;
    const int e = tid >> 5;
    const int j = tid & 31;
    const int b = blockIdx.x * 4 + e;

    h0[e][j]  = h1_in[b * 32 + j];
    h1l[e][j] = h1_in[32768 + b * 32 + j];
    __syncthreads();

    for (int t = 0; t < 2; ++t) {
        for (int c = j; c < 256; c += 32)
            xt[e][c] = g[(size_t)(t * 1024 + 4 * c + (b >> 8)) * 256 + (b & 255)];
        __syncthreads();

        // layer 0
        float gi0 = bih0[j], gi1 = bih0[32 + j], gi2 = bih0[64 + j];
        for (int c = 0; c < 256; ++c) {
            float xv = xt[e][c];
            gi0 += xv * wih0[j * 256 + c];
            gi1 += xv * wih0[(32 + j) * 256 + c];
            gi2 += xv * wih0[(64 + j) * 256 + c];
        }
        float gh0 = bhh0[j], gh1 = bhh0[32 + j], gh2 = bhh0[64 + j];
        #pragma unroll
        for (int c = 0; c < 32; ++c) {
            float hv = h0[e][c];
            gh0 += hv * whh0[j * 32 + c];
            gh1 += hv * whh0[(32 + j) * 32 + c];
            gh2 += hv * whh0[(64 + j) * 32 + c];
        }
        float r = 1.0f / (1.0f + expf(-(gi0 + gh0)));
        float z = 1.0f / (1.0f + expf(-(gi1 + gh1)));
        float nn = tanhf(gi2 + r * gh2);
        float hn0 = (1.0f - z) * nn + z * h0[e][j];
        __syncthreads();
        h0[e][j] = hn0;
        __syncthreads();

        // layer 1 (input = layer-0 output, 32-dim)
        float ai0 = bih1[j], ai1 = bih1[32 + j], ai2 = bih1[64 + j];
        #pragma unroll
        for (int c = 0; c < 32; ++c) {
            float xv = h0[e][c];
            ai0 += xv * wih1[j * 32 + c];
            ai1 += xv * wih1[(32 + j) * 32 + c];
            ai2 += xv * wih1[(64 + j) * 32 + c];
        }
        float ah0 = bhh1[j], ah1 = bhh1[32 + j], ah2 = bhh1[64 + j];
        #pragma unroll
        for (int c = 0; c < 32; ++c) {
            float hv = h1l[e][c];
            ah0 += hv * whh1[j * 32 + c];
            ah1 += hv * whh1[(32 + j) * 32 + c];
            ah2 += hv * whh1[(64 + j) * 32 + c];
        }
        float r1 = 1.0f / (1.0f + expf(-(ai0 + ah0)));
        float z1 = 1.0f / (1.0f + expf(-(ai1 + ah1)));
        float n1 = tanhf(ai2 + r1 * ah2);
        float hn1 = (1.0f - z1) * n1 + z1 * h1l[e][j];
        __syncthreads();
        h1l[e][j] = hn1;
        out1[(size_t)(t * 1024 + b) * 32 + j] = hn1;
        __syncthreads();
    }
    hT[b * 32 + j]         = h0[e][j];
    hT[32768 + b * 32 + j] = h1l[e][j];
}

// ---------------------------------------------------------------------------
// Kernel 3: head.  y[r] = relu( relu(yrow) . nn4_W + b ),
// yrow[c] = out1[t][(r'&31)*32 + c][r'>>5]
// ---------------------------------------------------------------------------
__global__ void k_final(const float* __restrict__ out1,
                        const float* __restrict__ nn4W, const float* __restrict__ nn4b,
                        float* __restrict__ y)
{
    const int r = blockIdx.x * 256 + threadIdx.x;
    if (r >= 2048) return;
    const int t = r >> 10, rp = r & 1023;
    const int f = rp >> 5, bb0 = (rp & 31) << 5;
    float acc = nn4b[0];
    #pragma unroll
    for (int c = 0; c < 32; ++c)
        acc += fmaxf(out1[(size_t)(t * 1024 + bb0 + c) * 32 + f], 0.0f) * nn4W[c];
    y[r] = fmaxf(acc, 0.0f);
}

extern "C" void kernel_launch(void* const* d_in, const int* in_sizes, int n_in,
                              void* d_out, int out_size, void* d_ws, size_t ws_size,
                              hipStream_t stream) {
    const float* x    = (const float*)d_in[0];
    // d_in[1] = batch (int32) — implied by contiguous 128-node blocks, unused
    const float* h1i  = (const float*)d_in[2];
    const float* W1   = (const float*)d_in[3];
    const float* b1   = (const float*)d_in[4];
    const float* W2   = (const float*)d_in[5];
    const float* b2   = (const float*)d_in[6];
    const float* nn1W = (const float*)d_in[7];
    const float* nn1b = (const float*)d_in[8];
    const float* nn2W = (const float*)d_in[9];
    const float* nn2b = (const float*)d_in[10];
    const float* nn4W = (const float*)d_in[11];
    const float* nn4b = (const float*)d_in[12];
    const float* wih0 = (const float*)d_in[13];
    const float* whh0 = (const float*)d_in[14];
    const float* bih0 = (const float*)d_in[15];
    const float* bhh0 = (const float*)d_in[16];
    const float* wih1 = (const float*)d_in[17];
    const float* whh1 = (const float*)d_in[18];
    const float* bih1 = (const float*)d_in[19];
    const float* bhh1 = (const float*)d_in[20];

    float* g_buf = (float*)d_ws;              // 2048*256 fp32
    float* out1  = g_buf + 2048 * 256;        // 2*1024*32 fp32

    float* y  = (float*)d_out;                // [2048]
    float* hT = y + 2048;                     // [2,1024,32]

    hipLaunchKernelGGL(k_graph, dim3(2048), dim3(256), 0, stream,
                       x, W1, b1, W2, b2, nn1W, nn1b, nn2W, nn2b, g_buf);
    hipLaunchKernelGGL(k_gru, dim3(256), dim3(128), 0, stream,
                       g_buf, h1i, wih0, whh0, bih0, bhh0,
                       wih1, whh1, bih1, bhh1, out1, hT);
    hipLaunchKernelGGL(k_final, dim3(8), dim3(256), 0, stream,
                       out1, nn4W, nn4b, y);
}

// Round 3
// 1662.630 us; speedup vs baseline: 4.0101x; 4.0101x over previous
//
#include <hip/hip_runtime.h>
#include <hip/hip_bf16.h>

// All tensors fp32. Output = [y (2048) | hT (2*1024*32)] fp32.
//
// Pipeline:
//   k_prep  : transpose/fold small weights into ws (W2T, nn2WT, WfT)
//   k_edge  : per (graph, half): KNN + EdgeConv MLP (lane-per-edge, scalar
//             weights) + shuffle aggregation + nn1 + nn2 + partial pooling
//   k_pool  : merge 2 partials per graph -> g[2048][256] (relu'd)
//   k_gru   : 2-layer GRU (T=2, B=1024, H=32) with torch reshape scramble
//   k_final : head -> y[2048]

#define NPER 128

// ---------------------------------------------------------------------------
// k_prep: W2T[128][64] = W2^T ; nn2WT[64][94] = nn2W^T ;
//         WfT[94][256]: [jj][r]: r<128 -> nn1W[r][jj] (max rows),
//                       r>=128 -> 0.25*nn1W[128+c][jj] + nn1W[256+c][jj]
// ---------------------------------------------------------------------------
__global__ void k_prep(const float* __restrict__ W2,
                       const float* __restrict__ nn2W,
                       const float* __restrict__ nn1W,
                       float* __restrict__ W2T, float* __restrict__ nn2WT,
                       float* __restrict__ WfT)
{
    int i = blockIdx.x * 256 + threadIdx.x;
    if (i < 8192) {                       // W2T: ch = i>>6, c = i&63
        W2T[i] = W2[(i & 63) * 128 + (i >> 6)];
    } else if (i < 8192 + 6016) {         // nn2WT: j = i-8192: ch=j/94, c=j%94
        int j = i - 8192, ch = j / 94, c = j - ch * 94;
        nn2WT[j] = nn2W[c * 64 + ch];
    } else if (i < 8192 + 6016 + 24064) { // WfT: k = i-14208: jj=k>>8, r=k&255
        int k = i - 14208, jj = k >> 8, r = k & 255;
        float v;
        if (r < 128) v = nn1W[r * 94 + jj];
        else {
            int c = r - 128;
            v = 0.25f * nn1W[(128 + c) * 94 + jj] + nn1W[(256 + c) * 94 + jj];
        }
        WfT[k] = v;
    }
}

// ---------------------------------------------------------------------------
// k_edge: block = (graph, half of 64 nodes), 256 threads = 4 waves.
// ---------------------------------------------------------------------------
__global__ __launch_bounds__(256, 2) void k_edge(
    const float* __restrict__ x,      // [N,5]
    const float* __restrict__ W1,     // [10,64]
    const float* __restrict__ b1,     // [64]
    const float* __restrict__ W2T,    // [128,64]
    const float* __restrict__ b2,     // [128]
    const float* __restrict__ WfT,    // [94,256]
    const float* __restrict__ nn1b,   // [94]
    const float* __restrict__ nn2WT,  // [64,94]
    const float* __restrict__ nn2b,   // [64]
    float* __restrict__ pmax,         // [4096,64]
    float* __restrict__ pmin,
    float* __restrict__ psum)
{
    __shared__ float xs[NPER * 5];          // 2.5 KB
    __shared__ int   nbr_s[64 * 4];         // 1 KB
    __shared__ float kd[4 * 4 * 64];        // 4 KB   [q][s][node]
    __shared__ int   ki[4 * 4 * 64];        // 4 KB
    __shared__ float aggM[64 * 65];         // 16.25 KB (padded)
    __shared__ float aggS[64 * 65];         // 16.25 KB
    __shared__ float nnh[64 * 97];          // 24.25 KB (padded)

    const int t = threadIdx.x;
    const int w = t >> 6;                   // wave id
    const int lane = t & 63;
    const int graph = blockIdx.x >> 1;
    const int node0 = (blockIdx.x & 1) * 64;

    // ---- stage x for the whole graph
    for (int i = t; i < NPER * 5; i += 256) xs[i] = x[(size_t)graph * (NPER * 5) + i];
    __syncthreads();

    // ---- KNN: 4 threads per node, each scans a quarter; stable insertion (<)
    {
        const int nl = t & 63;              // block-local node
        const int q  = t >> 6;
        const int n_g = node0 + nl;
        const float px = xs[n_g * 5 + 0], py = xs[n_g * 5 + 1], pz = xs[n_g * 5 + 2];
        float bd[4] = {3e38f, 3e38f, 3e38f, 3e38f};
        int   bi[4] = {0, 0, 0, 0};
        const int m0 = q * 32;
        for (int m = m0; m < m0 + 32; ++m) {
            if (m == n_g) continue;
            float dx = xs[m * 5 + 0] - px, dy = xs[m * 5 + 1] - py, dz = xs[m * 5 + 2] - pz;
            float d2 = __fadd_rn(__fadd_rn(__fmul_rn(dx, dx), __fmul_rn(dy, dy)),
                                 __fmul_rn(dz, dz));
            if (d2 < bd[3]) {
                int k = 3;
                while (k > 0 && d2 < bd[k - 1]) { bd[k] = bd[k - 1]; bi[k] = bi[k - 1]; --k; }
                bd[k] = d2; bi[k] = m;
            }
        }
        #pragma unroll
        for (int s = 0; s < 4; ++s) { kd[(q * 4 + s) * 64 + nl] = bd[s]; ki[(q * 4 + s) * 64 + nl] = bi[s]; }
    }
    __syncthreads();
    if (t < 64) {                           // merge quarters in global index order
        float bd[4] = {3e38f, 3e38f, 3e38f, 3e38f};
        int   bi[4] = {0, 0, 0, 0};
        #pragma unroll
        for (int q = 0; q < 4; ++q)
            #pragma unroll
            for (int s = 0; s < 4; ++s) {
                float d2 = kd[(q * 4 + s) * 64 + t];
                int   id = ki[(q * 4 + s) * 64 + t];
                if (d2 < bd[3]) {
                    int k = 3;
                    while (k > 0 && d2 < bd[k - 1]) { bd[k] = bd[k - 1]; bi[k] = bi[k - 1]; --k; }
                    bd[k] = d2; bi[k] = id;
                }
            }
        #pragma unroll
        for (int s = 0; s < 4; ++s) nbr_s[t * 4 + s] = bi[s];
    }
    __syncthreads();

    // ---- EdgeConv MLP1: lane-per-edge, h1 in registers, W1/b1 scalar loads
    const int nl = t >> 2;                  // block-local node of this edge
    const int kk = t & 3;
    const int n_g = node0 + nl;
    const int j   = nbr_s[nl * 4 + kk];
    float f[10];
    #pragma unroll
    for (int d = 0; d < 5; ++d) { f[d] = xs[n_g * 5 + d]; f[5 + d] = xs[j * 5 + d] - f[d]; }
    float h1v[64];
    #pragma unroll
    for (int c = 0; c < 64; ++c) h1v[c] = b1[c];
    #pragma unroll
    for (int d = 0; d < 10; ++d) {
        float fd = f[d];
        #pragma unroll
        for (int c = 0; c < 64; ++c) h1v[c] = fmaf(fd, W1[d * 64 + c], h1v[c]);
    }
    #pragma unroll
    for (int c = 0; c < 64; ++c) h1v[c] = fmaxf(h1v[c], 0.0f);

    // ---- two ch-halves: MLP2 + shuffle-agg, then nn1 partial (lane = node)
    float acc[24];
    const int jj0 = w * 24;
    const int jjN = (w == 3) ? 22 : 24;
    #pragma unroll
    for (int i = 0; i < 24; ++i) acc[i] = 0.0f;
    for (int i = 0; i < jjN; ++i) acc[i] = nn1b[jj0 + i];

    for (int h = 0; h < 2; ++h) {
        // MLP2 for ch in [h*64, h*64+64): scalar W2T rows, reduce over 4 edges
        for (int ch = 0; ch < 64; ++ch) {
            const float* wp = W2T + (size_t)(h * 64 + ch) * 64;
            float m = b2[h * 64 + ch];
            #pragma unroll
            for (int c = 0; c < 64; ++c) m = fmaf(h1v[c], wp[c], m);
            m = fmaxf(m, 0.0f);
            float mx = fmaxf(m, __shfl_xor(m, 1));
            mx = fmaxf(mx, __shfl_xor(mx, 2));
            float sm = m + __shfl_xor(m, 1);
            sm += __shfl_xor(sm, 2);
            if (kk == 0) { aggM[nl * 65 + ch] = mx; aggS[nl * 65 + ch] = sm; }
        }
        __syncthreads();

        // nn1 partial: lane = node, agg rows cached in regs, WfT scalar loads
        for (int cb = 0; cb < 64; cb += 16) {
            float am[16], as_[16];
            #pragma unroll
            for (int i = 0; i < 16; ++i) {
                am[i]  = aggM[lane * 65 + cb + i];
                as_[i] = aggS[lane * 65 + cb + i];
            }
            for (int i2 = 0; i2 < jjN; ++i2) {
                const float* wa = WfT + (size_t)(jj0 + i2) * 256 + h * 64 + cb;
                const float* wb = wa + 128;
                float a = acc[i2];
                #pragma unroll
                for (int i = 0; i < 16; ++i) a = fmaf(am[i], wa[i], fmaf(as_[i], wb[i], a));
                acc[i2] = a;
            }
        }
        __syncthreads();   // before next half overwrites agg
    }

    // ---- nnh = relu(nn1 out), lane = node
    for (int i2 = 0; i2 < jjN; ++i2) nnh[lane * 97 + jj0 + i2] = fmaxf(acc[i2], 0.0f);
    __syncthreads();

    // ---- nn2: lane = node, wave owns 16 output channels, nn2WT scalar loads
    {
        const int ch0 = w * 16;
        float acc2[16];
        #pragma unroll
        for (int i = 0; i < 16; ++i) acc2[i] = nn2b[ch0 + i];
        for (int cb = 0; cb < 94; cb += 32) {
            const int cn = (cb == 64) ? 30 : 32;
            float hv[32];
            for (int i = 0; i < cn; ++i) hv[i] = nnh[lane * 97 + cb + i];
            #pragma unroll
            for (int i = 0; i < 16; ++i) {
                const float* wp = nn2WT + (size_t)(ch0 + i) * 94 + cb;
                float a = acc2[i];
                for (int c = 0; c < cn; ++c) a = fmaf(hv[c], wp[c], a);
                acc2[i] = a;
            }
        }
        __syncthreads();   // agg buffers dead; reuse aggM as htile[64][65]
        #pragma unroll
        for (int i = 0; i < 16; ++i) aggM[lane * 65 + ch0 + i] = acc2[i];
    }
    __syncthreads();

    // ---- partial pooling over this block's 64 nodes
    if (t < 64) {
        float mx = -3e38f, mn = 3e38f, sm = 0.0f;
        for (int n = 0; n < 64; ++n) {
            float v = aggM[n * 65 + t];
            mx = fmaxf(mx, v); mn = fminf(mn, v); sm += v;
        }
        pmax[(size_t)blockIdx.x * 64 + t] = mx;
        pmin[(size_t)blockIdx.x * 64 + t] = mn;
        psum[(size_t)blockIdx.x * 64 + t] = sm;
    }
}

// ---------------------------------------------------------------------------
// k_pool: merge the two halves of each graph -> g[2048][256] (relu'd)
// block 256 = 4 waves = 4 graphs; lane = ch
// ---------------------------------------------------------------------------
__global__ void k_pool(const float* __restrict__ pmax, const float* __restrict__ pmin,
                       const float* __restrict__ psum, float* __restrict__ g_out)
{
    const int t = threadIdx.x;
    const int g = blockIdx.x * 4 + (t >> 6);
    const int ch = t & 63;
    const size_t a = (size_t)(2 * g) * 64 + ch, b = a + 64;
    float mx = fmaxf(pmax[a], pmax[b]);
    float mn = fminf(pmin[a], pmin[b]);
    float sm = psum[a] + psum[b];
    float* gp = g_out + (size_t)g * 256;
    gp[ch]        = fmaxf(mx, 0.0f);
    gp[64 + ch]   = fmaxf(mn, 0.0f);
    gp[128 + ch]  = fmaxf(sm, 0.0f);
    gp[192 + ch]  = fmaxf(sm * (1.0f / 128.0f), 0.0f);
}

// ---------------------------------------------------------------------------
// k_gru: unchanged from R2 (verified)
// ---------------------------------------------------------------------------
__global__ __launch_bounds__(128) void k_gru(
    const float* __restrict__ g, const float* __restrict__ h1_in,
    const float* __restrict__ wih0, const float* __restrict__ whh0,
    const float* __restrict__ bih0, const float* __restrict__ bhh0,
    const float* __restrict__ wih1, const float* __restrict__ whh1,
    const float* __restrict__ bih1, const float* __restrict__ bhh1,
    float* __restrict__ out1, float* __restrict__ hT)
{
    __shared__ float xt[4][256];
    __shared__ float h0[4][32];
    __shared__ float h1l[4][32];
    const int tid = threadIdx.x;
    const int e = tid >> 5;
    const int j = tid & 31;
    const int b = blockIdx.x * 4 + e;

    h0[e][j]  = h1_in[b * 32 + j];
    h1l[e][j] = h1_in[32768 + b * 32 + j];
    __syncthreads();

    for (int t = 0; t < 2; ++t) {
        for (int c = j; c < 256; c += 32)
            xt[e][c] = g[(size_t)(t * 1024 + 4 * c + (b >> 8)) * 256 + (b & 255)];
        __syncthreads();

        float gi0 = bih0[j], gi1 = bih0[32 + j], gi2 = bih0[64 + j];
        for (int c = 0; c < 256; ++c) {
            float xv = xt[e][c];
            gi0 += xv * wih0[j * 256 + c];
            gi1 += xv * wih0[(32 + j) * 256 + c];
            gi2 += xv * wih0[(64 + j) * 256 + c];
        }
        float gh0 = bhh0[j], gh1 = bhh0[32 + j], gh2 = bhh0[64 + j];
        #pragma unroll
        for (int c = 0; c < 32; ++c) {
            float hv = h0[e][c];
            gh0 += hv * whh0[j * 32 + c];
            gh1 += hv * whh0[(32 + j) * 32 + c];
            gh2 += hv * whh0[(64 + j) * 32 + c];
        }
        float r = 1.0f / (1.0f + expf(-(gi0 + gh0)));
        float z = 1.0f / (1.0f + expf(-(gi1 + gh1)));
        float nn = tanhf(gi2 + r * gh2);
        float hn0 = (1.0f - z) * nn + z * h0[e][j];
        __syncthreads();
        h0[e][j] = hn0;
        __syncthreads();

        float ai0 = bih1[j], ai1 = bih1[32 + j], ai2 = bih1[64 + j];
        #pragma unroll
        for (int c = 0; c < 32; ++c) {
            float xv = h0[e][c];
            ai0 += xv * wih1[j * 32 + c];
            ai1 += xv * wih1[(32 + j) * 32 + c];
            ai2 += xv * wih1[(64 + j) * 32 + c];
        }
        float ah0 = bhh1[j], ah1 = bhh1[32 + j], ah2 = bhh1[64 + j];
        #pragma unroll
        for (int c = 0; c < 32; ++c) {
            float hv = h1l[e][c];
            ah0 += hv * whh1[j * 32 + c];
            ah1 += hv * whh1[(32 + j) * 32 + c];
            ah2 += hv * whh1[(64 + j) * 32 + c];
        }
        float r1 = 1.0f / (1.0f + expf(-(ai0 + ah0)));
        float z1 = 1.0f / (1.0f + expf(-(ai1 + ah1)));
        float n1 = tanhf(ai2 + r1 * ah2);
        float hn1 = (1.0f - z1) * n1 + z1 * h1l[e][j];
        __syncthreads();
        h1l[e][j] = hn1;
        out1[(size_t)(t * 1024 + b) * 32 + j] = hn1;
        __syncthreads();
    }
    hT[b * 32 + j]         = h0[e][j];
    hT[32768 + b * 32 + j] = h1l[e][j];
}

__global__ void k_final(const float* __restrict__ out1,
                        const float* __restrict__ nn4W, const float* __restrict__ nn4b,
                        float* __restrict__ y)
{
    const int r = blockIdx.x * 256 + threadIdx.x;
    if (r >= 2048) return;
    const int t = r >> 10, rp = r & 1023;
    const int f = rp >> 5, bb0 = (rp & 31) << 5;
    float acc = nn4b[0];
    #pragma unroll
    for (int c = 0; c < 32; ++c)
        acc += fmaxf(out1[(size_t)(t * 1024 + bb0 + c) * 32 + f], 0.0f) * nn4W[c];
    y[r] = fmaxf(acc, 0.0f);
}

extern "C" void kernel_launch(void* const* d_in, const int* in_sizes, int n_in,
                              void* d_out, int out_size, void* d_ws, size_t ws_size,
                              hipStream_t stream) {
    const float* x    = (const float*)d_in[0];
    const float* h1i  = (const float*)d_in[2];
    const float* W1   = (const float*)d_in[3];
    const float* b1   = (const float*)d_in[4];
    const float* W2   = (const float*)d_in[5];
    const float* b2   = (const float*)d_in[6];
    const float* nn1W = (const float*)d_in[7];
    const float* nn1b = (const float*)d_in[8];
    const float* nn2W = (const float*)d_in[9];
    const float* nn2b = (const float*)d_in[10];
    const float* nn4W = (const float*)d_in[11];
    const float* nn4b = (const float*)d_in[12];
    const float* wih0 = (const float*)d_in[13];
    const float* whh0 = (const float*)d_in[14];
    const float* bih0 = (const float*)d_in[15];
    const float* bhh0 = (const float*)d_in[16];
    const float* wih1 = (const float*)d_in[17];
    const float* whh1 = (const float*)d_in[18];
    const float* bih1 = (const float*)d_in[19];
    const float* bhh1 = (const float*)d_in[20];

    float* ws = (float*)d_ws;
    float* g_buf  = ws;                   // 524288
    float* out1   = g_buf + 524288;       // 65536
    float* W2T    = out1 + 65536;         // 8192
    float* nn2WT  = W2T + 8192;           // 6016
    float* WfT    = nn2WT + 6016;         // 24064
    float* pmax   = WfT + 24064;          // 262144
    float* pmin   = pmax + 262144;        // 262144
    float* psum   = pmin + 262144;        // 262144

    float* y  = (float*)d_out;            // [2048]
    float* hT = y + 2048;                 // [2,1024,32]

    hipLaunchKernelGGL(k_prep, dim3(150), dim3(256), 0, stream,
                       W2, nn2W, nn1W, W2T, nn2WT, WfT);
    hipLaunchKernelGGL(k_edge, dim3(4096), dim3(256), 0, stream,
                       x, W1, b1, W2T, b2, WfT, nn1b, nn2WT, nn2b,
                       pmax, pmin, psum);
    hipLaunchKernelGGL(k_pool, dim3(512), dim3(256), 0, stream,
                       pmax, pmin, psum, g_buf);
    hipLaunchKernelGGL(k_gru, dim3(256), dim3(128), 0, stream,
                       g_buf, h1i, wih0, whh0, bih0, bhh0,
                       wih1, whh1, bih1, bhh1, out1, hT);
    hipLaunchKernelGGL(k_final, dim3(8), dim3(256), 0, stream,
                       out1, nn4W, nn4b, y);
}

// Round 5
// 1570.252 us; speedup vs baseline: 4.2460x; 1.0588x over previous
//
#include <hip/hip_runtime.h>
#include <hip/hip_bf16.h>

// All tensors fp32. Output = [y (2048) | hT (2*1024*32)] fp32.
#define NPER 128

// ---------------------------------------------------------------------------
// k_prep: W2I[32][64][4]  : W2I[((ch>>2)*64 + c)*4 + (ch&3)] = W2[c*128+ch]
//         nn2WT[64][94]   : nn2W^T
//         WfT[96][256]    : [jj][r]: r<128 -> nn1W[r][jj] (max rows),
//                           r>=128 -> 0.25*nn1W[128+c][jj] + nn1W[256+c][jj]
//                           rows 94,95 zero (padding for fixed trip count)
// ---------------------------------------------------------------------------
__global__ void k_prep(const float* __restrict__ W2,
                       const float* __restrict__ nn2W,
                       const float* __restrict__ nn1W,
                       float* __restrict__ W2I, float* __restrict__ nn2WT,
                       float* __restrict__ WfT)
{
    int i = blockIdx.x * 256 + threadIdx.x;
    if (i < 8192) {                       // W2I
        int ch4 = i >> 8, rem = i & 255, c = rem >> 2, sub = rem & 3;
        W2I[i] = W2[c * 128 + (ch4 * 4 + sub)];
    } else if (i < 8192 + 6016) {         // nn2WT
        int j = i - 8192, ch = j / 94, c = j - ch * 94;
        nn2WT[j] = nn2W[c * 64 + ch];
    } else if (i < 8192 + 6016 + 24576) { // WfT (96 rows x 256)
        int k = i - 14208, jj = k >> 8, r = k & 255;
        float v = 0.0f;
        if (jj < 94) {
            if (r < 128) v = nn1W[r * 94 + jj];
            else {
                int c = r - 128;
                v = 0.25f * nn1W[(128 + c) * 94 + jj] + nn1W[(256 + c) * 94 + jj];
            }
        }
        WfT[k] = v;
    }
}

// ---------------------------------------------------------------------------
// k_edge: block = (graph, half of 64 nodes), 256 threads = 4 waves.
// ---------------------------------------------------------------------------
__global__ __launch_bounds__(256, 2) void k_edge(
    const float* __restrict__ x,      // [N,5]
    const float* __restrict__ W1,     // [10,64]
    const float* __restrict__ b1,     // [64]
    const float* __restrict__ W2I,    // [32][64][4]
    const float* __restrict__ b2,     // [128]
    const float* __restrict__ WfT,    // [96,256]
    const float* __restrict__ nn1b,   // [94]
    const float* __restrict__ nn2WT,  // [64,94]
    const float* __restrict__ nn2b,   // [64]
    float* __restrict__ pmax,         // [4096,64]
    float* __restrict__ pmin,
    float* __restrict__ psum)
{
    __shared__ float xs[NPER * 5];          // 2.5 KB
    __shared__ int   nbr_s[64 * 4];         // 1 KB
    __shared__ float kd[4 * 4 * 64];        // 4 KB   [q][s][node]
    __shared__ int   ki[4 * 4 * 64];        // 4 KB
    __shared__ float aggM[64 * 68];         // 17 KB (pad 68 -> b128-aligned)
    __shared__ float aggS[64 * 68];         // 17 KB
    __shared__ float nnh[64 * 97];          // 24.25 KB

    const int t = threadIdx.x;
    const int w = t >> 6;                   // wave id
    const int lane = t & 63;
    const int graph = blockIdx.x >> 1;
    const int node0 = (blockIdx.x & 1) * 64;

    for (int i = t; i < NPER * 5; i += 256) xs[i] = x[(size_t)graph * (NPER * 5) + i];
    __syncthreads();

    // ---- KNN: 4 threads per node, each scans a quarter; stable insertion (<)
    {
        const int nl2 = t & 63;
        const int q  = t >> 6;
        const int n_g = node0 + nl2;
        const float px = xs[n_g * 5 + 0], py = xs[n_g * 5 + 1], pz = xs[n_g * 5 + 2];
        float bd[4] = {3e38f, 3e38f, 3e38f, 3e38f};
        int   bi[4] = {0, 0, 0, 0};
        const int m0 = q * 32;
        for (int m = m0; m < m0 + 32; ++m) {
            if (m == n_g) continue;
            float dx = xs[m * 5 + 0] - px, dy = xs[m * 5 + 1] - py, dz = xs[m * 5 + 2] - pz;
            float d2 = __fadd_rn(__fadd_rn(__fmul_rn(dx, dx), __fmul_rn(dy, dy)),
                                 __fmul_rn(dz, dz));
            if (d2 < bd[3]) {
                int k = 3;
                while (k > 0 && d2 < bd[k - 1]) { bd[k] = bd[k - 1]; bi[k] = bi[k - 1]; --k; }
                bd[k] = d2; bi[k] = m;
            }
        }
        #pragma unroll
        for (int s = 0; s < 4; ++s) { kd[(q * 4 + s) * 64 + nl2] = bd[s]; ki[(q * 4 + s) * 64 + nl2] = bi[s]; }
    }
    __syncthreads();
    if (t < 64) {                           // merge quarters in global index order
        float bd[4] = {3e38f, 3e38f, 3e38f, 3e38f};
        int   bi[4] = {0, 0, 0, 0};
        #pragma unroll
        for (int q = 0; q < 4; ++q)
            #pragma unroll
            for (int s = 0; s < 4; ++s) {
                float d2 = kd[(q * 4 + s) * 64 + t];
                int   id = ki[(q * 4 + s) * 64 + t];
                if (d2 < bd[3]) {
                    int k = 3;
                    while (k > 0 && d2 < bd[k - 1]) { bd[k] = bd[k - 1]; bi[k] = bi[k - 1]; --k; }
                    bd[k] = d2; bi[k] = id;
                }
            }
        #pragma unroll
        for (int s = 0; s < 4; ++s) nbr_s[t * 4 + s] = bi[s];
    }
    __syncthreads();

    // ---- EdgeConv MLP1: lane-per-edge, h1 in registers (10 outer x 64 inner: high ILP)
    const int nl = t >> 2;
    const int kk = t & 3;
    const int n_g = node0 + nl;
    const int j   = nbr_s[nl * 4 + kk];
    float f[10];
    #pragma unroll
    for (int d = 0; d < 5; ++d) { f[d] = xs[n_g * 5 + d]; f[5 + d] = xs[j * 5 + d] - f[d]; }
    float h1v[64];
    #pragma unroll
    for (int c = 0; c < 64; ++c) h1v[c] = b1[c];
    #pragma unroll
    for (int d = 0; d < 10; ++d) {
        float fd = f[d];
        #pragma unroll
        for (int c = 0; c < 64; ++c) h1v[c] = fmaf(fd, W1[d * 64 + c], h1v[c]);
    }
    #pragma unroll
    for (int c = 0; c < 64; ++c) h1v[c] = fmaxf(h1v[c], 0.0f);

    // ---- nn1 accumulators (wave owns 24 jj channels for node = lane)
    float acc[24];
    const int jj0 = w * 24;
    #pragma unroll
    for (int i = 0; i < 24; ++i) acc[i] = (jj0 + i < 94) ? nn1b[jj0 + i] : 0.0f;

    for (int h = 0; h < 2; ++h) {
        // MLP2: 16 groups of 4 channels -> 4 independent FMA chains
        for (int ch = 0; ch < 64; ch += 4) {
            const float* wp = W2I + (size_t)(h * 16 + (ch >> 2)) * 256;
            float m0 = b2[h * 64 + ch], m1 = b2[h * 64 + ch + 1];
            float m2 = b2[h * 64 + ch + 2], m3 = b2[h * 64 + ch + 3];
            #pragma unroll
            for (int c = 0; c < 64; ++c) {
                float hv = h1v[c];
                m0 = fmaf(hv, wp[c * 4 + 0], m0);
                m1 = fmaf(hv, wp[c * 4 + 1], m1);
                m2 = fmaf(hv, wp[c * 4 + 2], m2);
                m3 = fmaf(hv, wp[c * 4 + 3], m3);
            }
            m0 = fmaxf(m0, 0.0f); m1 = fmaxf(m1, 0.0f);
            m2 = fmaxf(m2, 0.0f); m3 = fmaxf(m3, 0.0f);
            // reduce across the node's 4 edge lanes (xor 1, xor 2)
            float x0 = fmaxf(m0, __shfl_xor(m0, 1));
            float x1 = fmaxf(m1, __shfl_xor(m1, 1));
            float x2 = fmaxf(m2, __shfl_xor(m2, 1));
            float x3 = fmaxf(m3, __shfl_xor(m3, 1));
            x0 = fmaxf(x0, __shfl_xor(x0, 2));
            x1 = fmaxf(x1, __shfl_xor(x1, 2));
            x2 = fmaxf(x2, __shfl_xor(x2, 2));
            x3 = fmaxf(x3, __shfl_xor(x3, 2));
            float s0 = m0 + __shfl_xor(m0, 1);
            float s1 = m1 + __shfl_xor(m1, 1);
            float s2 = m2 + __shfl_xor(m2, 1);
            float s3 = m3 + __shfl_xor(m3, 1);
            s0 += __shfl_xor(s0, 2);
            s1 += __shfl_xor(s1, 2);
            s2 += __shfl_xor(s2, 2);
            s3 += __shfl_xor(s3, 2);
            if (kk == 0) {
                *(float4*)&aggM[nl * 68 + ch] = make_float4(x0, x1, x2, x3);
                *(float4*)&aggS[nl * 68 + ch] = make_float4(s0, s1, s2, s3);
            }
        }
        __syncthreads();

        // nn1 partial: lane = node; agg rows cached via b128; 24 indep chains
        for (int cb = 0; cb < 64; cb += 16) {
            float am[16], as_[16];
            #pragma unroll
            for (int i = 0; i < 4; ++i) {
                *(float4*)&am[i * 4]  = *(const float4*)&aggM[lane * 68 + cb + i * 4];
                *(float4*)&as_[i * 4] = *(const float4*)&aggS[lane * 68 + cb + i * 4];
            }
            #pragma unroll 2
            for (int i2 = 0; i2 < 24; ++i2) {
                const float* wa = WfT + (size_t)(jj0 + i2) * 256 + h * 64 + cb;
                const float* wb = wa + 128;
                float a = acc[i2];
                #pragma unroll
                for (int i = 0; i < 16; ++i) a = fmaf(am[i], wa[i], fmaf(as_[i], wb[i], a));
                acc[i2] = a;
            }
        }
        __syncthreads();   // before next half overwrites agg
    }

    // ---- nnh = relu(nn1 out)
    #pragma unroll
    for (int i2 = 0; i2 < 24; ++i2)
        if (jj0 + i2 < 94) nnh[lane * 97 + jj0 + i2] = fmaxf(acc[i2], 0.0f);
    __syncthreads();

    // ---- nn2: lane = node, wave owns 16 output channels
    {
        const int ch0 = w * 16;
        float acc2[16];
        #pragma unroll
        for (int i = 0; i < 16; ++i) acc2[i] = nn2b[ch0 + i];
        for (int cb = 0; cb < 94; cb += 32) {
            const int cn = (cb == 64) ? 30 : 32;
            float hv[32];
            for (int i = 0; i < cn; ++i) hv[i] = nnh[lane * 97 + cb + i];
            #pragma unroll
            for (int i = 0; i < 16; ++i) {
                const float* wp = nn2WT + (size_t)(ch0 + i) * 94 + cb;
                float a = acc2[i];
                for (int c = 0; c < cn; ++c) a = fmaf(hv[c], wp[c], a);
                acc2[i] = a;
            }
        }
        __syncthreads();   // agg buffers dead; reuse aggM as htile[64][68]
        #pragma unroll
        for (int i = 0; i < 4; ++i)
            *(float4*)&aggM[lane * 68 + ch0 + i * 4] =
                make_float4(acc2[i * 4], acc2[i * 4 + 1], acc2[i * 4 + 2], acc2[i * 4 + 3]);
    }
    __syncthreads();

    // ---- partial pooling over this block's 64 nodes
    if (t < 64) {
        float mx = -3e38f, mn = 3e38f, sm = 0.0f;
        for (int n = 0; n < 64; ++n) {
            float v = aggM[n * 68 + t];
            mx = fmaxf(mx, v); mn = fminf(mn, v); sm += v;
        }
        pmax[(size_t)blockIdx.x * 64 + t] = mx;
        pmin[(size_t)blockIdx.x * 64 + t] = mn;
        psum[(size_t)blockIdx.x * 64 + t] = sm;
    }
}

// ---------------------------------------------------------------------------
__global__ void k_pool(const float* __restrict__ pmax, const float* __restrict__ pmin,
                       const float* __restrict__ psum, float* __restrict__ g_out)
{
    const int t = threadIdx.x;
    const int g = blockIdx.x * 4 + (t >> 6);
    const int ch = t & 63;
    const size_t a = (size_t)(2 * g) * 64 + ch, b = a + 64;
    float mx = fmaxf(pmax[a], pmax[b]);
    float mn = fminf(pmin[a], pmin[b]);
    float sm = psum[a] + psum[b];
    float* gp = g_out + (size_t)g * 256;
    gp[ch]        = fmaxf(mx, 0.0f);
    gp[64 + ch]   = fmaxf(mn, 0.0f);
    gp[128 + ch]  = fmaxf(sm, 0.0f);
    gp[192 + ch]  = fmaxf(sm * (1.0f / 128.0f), 0.0f);
}

// ---------------------------------------------------------------------------
__global__ __launch_bounds__(128) void k_gru(
    const float* __restrict__ g, const float* __restrict__ h1_in,
    const float* __restrict__ wih0, const float* __restrict__ whh0,
    const float* __restrict__ bih0, const float* __restrict__ bhh0,
    const float* __restrict__ wih1, const float* __restrict__ whh1,
    const float* __restrict__ bih1, const float* __restrict__ bhh1,
    float* __restrict__ out1, float* __restrict__ hT)
{
    __shared__ float xt[4][256];
    __shared__ float h0[4][32];
    __shared__ float h1l[4][32];
    const int tid = threadIdx.x;
    const int e = tid >> 5;
    const int j = tid & 31;
    const int b = blockIdx.x * 4 + e;

    h0[e][j]  = h1_in[b * 32 + j];
    h1l[e][j] = h1_in[32768 + b * 32 + j];
    __syncthreads();

    for (int t = 0; t < 2; ++t) {
        for (int c = j; c < 256; c += 32)
            xt[e][c] = g[(size_t)(t * 1024 + 4 * c + (b >> 8)) * 256 + (b & 255)];
        __syncthreads();

        float gi0 = bih0[j], gi1 = bih0[32 + j], gi2 = bih0[64 + j];
        for (int c = 0; c < 256; ++c) {
            float xv = xt[e][c];
            gi0 += xv * wih0[j * 256 + c];
            gi1 += xv * wih0[(32 + j) * 256 + c];
            gi2 += xv * wih0[(64 + j) * 256 + c];
        }
        float gh0 = bhh0[j], gh1 = bhh0[32 + j], gh2 = bhh0[64 + j];
        #pragma unroll
        for (int c = 0; c < 32; ++c) {
            float hv = h0[e][c];
            gh0 += hv * whh0[j * 32 + c];
            gh1 += hv * whh0[(32 + j) * 32 + c];
            gh2 += hv * whh0[(64 + j) * 32 + c];
        }
        float r = 1.0f / (1.0f + expf(-(gi0 + gh0)));
        float z = 1.0f / (1.0f + expf(-(gi1 + gh1)));
        float nn = tanhf(gi2 + r * gh2);
        float hn0 = (1.0f - z) * nn + z * h0[e][j];
        __syncthreads();
        h0[e][j] = hn0;
        __syncthreads();

        float ai0 = bih1[j], ai1 = bih1[32 + j], ai2 = bih1[64 + j];
        #pragma unroll
        for (int c = 0; c < 32; ++c) {
            float xv = h0[e][c];
            ai0 += xv * wih1[j * 32 + c];
            ai1 += xv * wih1[(32 + j) * 32 + c];
            ai2 += xv * wih1[(64 + j) * 32 + c];
        }
        float ah0 = bhh1[j], ah1 = bhh1[32 + j], ah2 = bhh1[64 + j];
        #pragma unroll
        for (int c = 0; c < 32; ++c) {
            float hv = h1l[e][c];
            ah0 += hv * whh1[j * 32 + c];
            ah1 += hv * whh1[(32 + j) * 32 + c];
            ah2 += hv * whh1[(64 + j) * 32 + c];
        }
        float r1 = 1.0f / (1.0f + expf(-(ai0 + ah0)));
        float z1 = 1.0f / (1.0f + expf(-(ai1 + ah1)));
        float n1 = tanhf(ai2 + r1 * ah2);
        float hn1 = (1.0f - z1) * n1 + z1 * h1l[e][j];
        __syncthreads();
        h1l[e][j] = hn1;
        out1[(size_t)(t * 1024 + b) * 32 + j] = hn1;
        __syncthreads();
    }
    hT[b * 32 + j]         = h0[e][j];
    hT[32768 + b * 32 + j] = h1l[e][j];
}

__global__ void k_final(const float* __restrict__ out1,
                        const float* __restrict__ nn4W, const float* __restrict__ nn4b,
                        float* __restrict__ y)
{
    const int r = blockIdx.x * 256 + threadIdx.x;
    if (r >= 2048) return;
    const int t = r >> 10, rp = r & 1023;
    const int f = rp >> 5, bb0 = (rp & 31) << 5;
    float acc = nn4b[0];
    #pragma unroll
    for (int c = 0; c < 32; ++c)
        acc += fmaxf(out1[(size_t)(t * 1024 + bb0 + c) * 32 + f], 0.0f) * nn4W[c];
    y[r] = fmaxf(acc, 0.0f);
}

extern "C" void kernel_launch(void* const* d_in, const int* in_sizes, int n_in,
                              void* d_out, int out_size, void* d_ws, size_t ws_size,
                              hipStream_t stream) {
    const float* x    = (const float*)d_in[0];
    const float* h1i  = (const float*)d_in[2];
    const float* W1   = (const float*)d_in[3];
    const float* b1   = (const float*)d_in[4];
    const float* W2   = (const float*)d_in[5];
    const float* b2   = (const float*)d_in[6];
    const float* nn1W = (const float*)d_in[7];
    const float* nn1b = (const float*)d_in[8];
    const float* nn2W = (const float*)d_in[9];
    const float* nn2b = (const float*)d_in[10];
    const float* nn4W = (const float*)d_in[11];
    const float* nn4b = (const float*)d_in[12];
    const float* wih0 = (const float*)d_in[13];
    const float* whh0 = (const float*)d_in[14];
    const float* bih0 = (const float*)d_in[15];
    const float* bhh0 = (const float*)d_in[16];
    const float* wih1 = (const float*)d_in[17];
    const float* whh1 = (const float*)d_in[18];
    const float* bih1 = (const float*)d_in[19];
    const float* bhh1 = (const float*)d_in[20];

    float* ws = (float*)d_ws;
    float* g_buf  = ws;                   // 524288
    float* out1   = g_buf + 524288;       // 65536
    float* W2I    = out1 + 65536;         // 8192
    float* nn2WT  = W2I + 8192;           // 6016
    float* WfT    = nn2WT + 6016;         // 24576 (96x256)
    float* pmax   = WfT + 24576;          // 262144
    float* pmin   = pmax + 262144;        // 262144
    float* psum   = pmin + 262144;        // 262144

    float* y  = (float*)d_out;            // [2048]
    float* hT = y + 2048;                 // [2,1024,32]

    hipLaunchKernelGGL(k_prep, dim3(152), dim3(256), 0, stream,
                       W2, nn2W, nn1W, W2I, nn2WT, WfT);
    hipLaunchKernelGGL(k_edge, dim3(4096), dim3(256), 0, stream,
                       x, W1, b1, W2I, b2, WfT, nn1b, nn2WT, nn2b,
                       pmax, pmin, psum);
    hipLaunchKernelGGL(k_pool, dim3(512), dim3(256), 0, stream,
                       pmax, pmin, psum, g_buf);
    hipLaunchKernelGGL(k_gru, dim3(256), dim3(128), 0, stream,
                       g_buf, h1i, wih0, whh0, bih0, bhh0,
                       wih1, whh1, bih1, bhh1, out1, hT);
    hipLaunchKernelGGL(k_final, dim3(8), dim3(256), 0, stream,
                       out1, nn4W, nn4b, y);
}

// Round 8
// 1153.705 us; speedup vs baseline: 5.7791x; 1.3611x over previous
//
#include <hip/hip_runtime.h>
#include <hip/hip_bf16.h>

// All tensors fp32. Output = [y (2048) | hT (2*1024*32)] fp32.
#define NPER 128

// branchless stable top-4 insert, strict < (earlier candidate wins ties)
__device__ __forceinline__ void ins4(float d, int id, float* bd, int* bi) {
    const bool c0 = d < bd[0], c1 = d < bd[1], c2 = d < bd[2], c3 = d < bd[3];
    bd[3] = c2 ? bd[2] : (c3 ? d : bd[3]);  bi[3] = c2 ? bi[2] : (c3 ? id : bi[3]);
    bd[2] = c1 ? bd[1] : (c2 ? d : bd[2]);  bi[2] = c1 ? bi[1] : (c2 ? id : bi[2]);
    bd[1] = c0 ? bd[0] : (c1 ? d : bd[1]);  bi[1] = c0 ? bi[0] : (c1 ? id : bi[1]);
    bd[0] = c0 ? d : bd[0];                 bi[0] = c0 ? id : bi[0];
}

// ---------------------------------------------------------------------------
// k_prep (R4-verified): W2I[32][64][4]; nn2WT[64][94]; WfT[96][256]
// ---------------------------------------------------------------------------
__global__ void k_prep(const float* __restrict__ W2,
                       const float* __restrict__ nn2W,
                       const float* __restrict__ nn1W,
                       float* __restrict__ W2I, float* __restrict__ nn2WT,
                       float* __restrict__ WfT)
{
    int i = blockIdx.x * 256 + threadIdx.x;
    if (i < 8192) {                       // W2I
        int ch4 = i >> 8, rem = i & 255, c = rem >> 2, sub = rem & 3;
        W2I[i] = W2[c * 128 + (ch4 * 4 + sub)];
    } else if (i < 8192 + 6016) {         // nn2WT
        int j = i - 8192, ch = j / 94, c = j - ch * 94;
        nn2WT[j] = nn2W[c * 64 + ch];
    } else if (i < 8192 + 6016 + 24576) { // WfT (96 rows x 256)
        int k = i - 14208, jj = k >> 8, r = k & 255;
        float v = 0.0f;
        if (jj < 94) {
            if (r < 128) v = nn1W[r * 94 + jj];
            else {
                int c = r - 128;
                v = 0.25f * nn1W[(128 + c) * 94 + jj] + nn1W[(256 + c) * 94 + jj];
            }
        }
        WfT[k] = v;
    }
}

// ---------------------------------------------------------------------------
// k_edge: block = (graph, half of 64 nodes), 256 threads = 4 waves.
// R5-verified math; branchless KNN; scalarized (s_load) nn1/nn2 weights;
// 42.2 KB phase-aliased LDS pool -> 3 blocks/CU.
// ---------------------------------------------------------------------------
__global__ __launch_bounds__(256, 3) void k_edge(
    const float* __restrict__ x,      // [N,5]
    const float* __restrict__ W1,     // [10,64]
    const float* __restrict__ b1,     // [64]
    const float* __restrict__ W2I,    // [32][64][4]
    const float* __restrict__ b2,     // [128]
    const float* __restrict__ WfT,    // [96,256]
    const float* __restrict__ nn1b,   // [94]
    const float* __restrict__ nn2WT,  // [64,94]
    const float* __restrict__ nn2b,   // [64]
    float* __restrict__ pmax,         // [4096,64]
    float* __restrict__ pmin,
    float* __restrict__ psum)
{
    __shared__ float pool[10560];     // 42240 B
    float* XS  = pool;                      // [640]   phase 1
    float* KD  = pool + 640;                // [1024]  phase 1
    int*   KI  = (int*)(pool + 1664);       // [1024]  phase 1
    int*   NBR = (int*)(pool + 2688);       // [256]   phase 1
    float* AGM = pool;                      // [4352]  phase 2 (64x68)
    float* AGS = pool + 4352;               // [4352]  phase 2
    float* NNH = pool;                      // [6208]  phase 3 (64x97)
    float* HT  = pool + 6208;               // [4352]  phase 3 (64x68)

    const int t = threadIdx.x;
    const int lane = t & 63;
    // wave id, forced into an SGPR so weight addresses become provably
    // wave-uniform -> compiler emits s_load for the weight blocks.
    const int w = __builtin_amdgcn_readfirstlane(t >> 6);
    const int graph = blockIdx.x >> 1;
    const int node0 = (blockIdx.x & 1) * 64;

    for (int i = t; i < NPER * 5; i += 256) XS[i] = x[(size_t)graph * (NPER * 5) + i];
    __syncthreads();

    // ---- KNN: 4 threads per node (q = t>>6), branchless insert, LDS merge
    {
        const int nl2 = t & 63;
        const int q  = t >> 6;
        const int ng2 = node0 + nl2;
        const float px = XS[ng2 * 5 + 0], py = XS[ng2 * 5 + 1], pz = XS[ng2 * 5 + 2];
        float bd[4] = {3e38f, 3e38f, 3e38f, 3e38f};
        int   bi[4] = {0, 0, 0, 0};
        const int m0 = q * 32;
        for (int m = m0; m < m0 + 32; ++m) {
            float dx = XS[m * 5 + 0] - px, dy = XS[m * 5 + 1] - py, dz = XS[m * 5 + 2] - pz;
            float d2 = __fadd_rn(__fadd_rn(__fmul_rn(dx, dx), __fmul_rn(dy, dy)),
                                 __fmul_rn(dz, dz));
            d2 = (m == ng2) ? 3.0e38f : d2;   // self never inserted (strict <)
            ins4(d2, m, bd, bi);
        }
        #pragma unroll
        for (int s = 0; s < 4; ++s) { KD[(q * 4 + s) * 64 + nl2] = bd[s]; KI[(q * 4 + s) * 64 + nl2] = bi[s]; }
    }
    __syncthreads();
    if (t < 64) {                           // merge quarters in global index order
        float bd[4] = {3e38f, 3e38f, 3e38f, 3e38f};
        int   bi[4] = {0, 0, 0, 0};
        #pragma unroll
        for (int q = 0; q < 4; ++q)
            #pragma unroll
            for (int s = 0; s < 4; ++s)
                ins4(KD[(q * 4 + s) * 64 + t], KI[(q * 4 + s) * 64 + t], bd, bi);
        #pragma unroll
        for (int s = 0; s < 4; ++s) NBR[t * 4 + s] = bi[s];
    }
    __syncthreads();

    // ---- MLP1: lane-per-edge, h1[64] in registers (W1/b1 uniform -> s_load)
    const int nl = t >> 2;
    const int kk = t & 3;
    const int n_g = node0 + nl;
    const int j   = NBR[nl * 4 + kk];
    float f[10];
    #pragma unroll
    for (int d = 0; d < 5; ++d) { f[d] = XS[n_g * 5 + d]; f[5 + d] = XS[j * 5 + d] - f[d]; }
    float h1v[64];
    #pragma unroll
    for (int c = 0; c < 64; ++c) h1v[c] = b1[c];
    #pragma unroll
    for (int d = 0; d < 10; ++d) {
        float fd = f[d];
        #pragma unroll
        for (int c = 0; c < 64; ++c) h1v[c] = fmaf(fd, W1[d * 64 + c], h1v[c]);
    }
    #pragma unroll
    for (int c = 0; c < 64; ++c) h1v[c] = fmaxf(h1v[c], 0.0f);
    __syncthreads();   // XS/NBR dead; AGM/AGS may alias them now

    // ---- nn1 accumulators (wave owns 24 jj channels, node = lane)
    float acc[24];
    const int jj0 = __builtin_amdgcn_readfirstlane(w * 24);
    #pragma unroll
    for (int i = 0; i < 24; ++i) acc[i] = (jj0 + i < 94) ? nn1b[jj0 + i] : 0.0f;

    for (int h = 0; h < 2; ++h) {
        // MLP2: 16 groups of 4 channels -> 4 independent FMA chains
        for (int ch = 0; ch < 64; ch += 4) {
            const float* wp = W2I + (size_t)(h * 16 + (ch >> 2)) * 256;  // uniform
            float m0 = b2[h * 64 + ch], m1 = b2[h * 64 + ch + 1];
            float m2 = b2[h * 64 + ch + 2], m3 = b2[h * 64 + ch + 3];
            #pragma unroll
            for (int c = 0; c < 64; ++c) {
                float hv = h1v[c];
                m0 = fmaf(hv, wp[c * 4 + 0], m0);
                m1 = fmaf(hv, wp[c * 4 + 1], m1);
                m2 = fmaf(hv, wp[c * 4 + 2], m2);
                m3 = fmaf(hv, wp[c * 4 + 3], m3);
            }
            m0 = fmaxf(m0, 0.0f); m1 = fmaxf(m1, 0.0f);
            m2 = fmaxf(m2, 0.0f); m3 = fmaxf(m3, 0.0f);
            float x0 = fmaxf(m0, __shfl_xor(m0, 1));
            float x1 = fmaxf(m1, __shfl_xor(m1, 1));
            float x2 = fmaxf(m2, __shfl_xor(m2, 1));
            float x3 = fmaxf(m3, __shfl_xor(m3, 1));
            x0 = fmaxf(x0, __shfl_xor(x0, 2));
            x1 = fmaxf(x1, __shfl_xor(x1, 2));
            x2 = fmaxf(x2, __shfl_xor(x2, 2));
            x3 = fmaxf(x3, __shfl_xor(x3, 2));
            float s0 = m0 + __shfl_xor(m0, 1);
            float s1 = m1 + __shfl_xor(m1, 1);
            float s2 = m2 + __shfl_xor(m2, 1);
            float s3 = m3 + __shfl_xor(m3, 1);
            s0 += __shfl_xor(s0, 2);
            s1 += __shfl_xor(s1, 2);
            s2 += __shfl_xor(s2, 2);
            s3 += __shfl_xor(s3, 2);
            if (kk == 0) {
                *(float4*)&AGM[nl * 68 + ch] = make_float4(x0, x1, x2, x3);
                *(float4*)&AGS[nl * 68 + ch] = make_float4(s0, s1, s2, s3);
            }
        }
        __syncthreads();

        // nn1 partial: lane = node; agg rows via b128; WfT via s_load (uniform)
        for (int cb = 0; cb < 64; cb += 16) {
            float am[16], as_[16];
            #pragma unroll
            for (int i = 0; i < 4; ++i) {
                *(float4*)&am[i * 4]  = *(const float4*)&AGM[lane * 68 + cb + i * 4];
                *(float4*)&as_[i * 4] = *(const float4*)&AGS[lane * 68 + cb + i * 4];
            }
            #pragma unroll 2
            for (int i2 = 0; i2 < 24; ++i2) {
                const float* wa = WfT + (size_t)(jj0 + i2) * 256 + h * 64 + cb;
                const float* wb = wa + 128;
                float a = acc[i2];
                #pragma unroll
                for (int i = 0; i < 16; ++i) a = fmaf(am[i], wa[i], fmaf(as_[i], wb[i], a));
                acc[i2] = a;
            }
        }
        __syncthreads();   // before next half overwrites agg / NNH alias
    }

    // ---- nnh = relu(nn1)
    #pragma unroll
    for (int i2 = 0; i2 < 24; ++i2)
        if (jj0 + i2 < 94) NNH[lane * 97 + jj0 + i2] = fmaxf(acc[i2], 0.0f);
    __syncthreads();

    // ---- nn2: lane = node, wave owns 16 output channels (weights s_load)
    {
        const int ch0 = __builtin_amdgcn_readfirstlane(w * 16);
        float acc2[16];
        #pragma unroll
        for (int i = 0; i < 16; ++i) acc2[i] = nn2b[ch0 + i];
        for (int cb = 0; cb < 94; cb += 32) {
            const int cn = (cb == 64) ? 30 : 32;
            float hv[32];
            for (int i = 0; i < cn; ++i) hv[i] = NNH[lane * 97 + cb + i];
            #pragma unroll
            for (int i = 0; i < 16; ++i) {
                const float* wp = nn2WT + (size_t)(ch0 + i) * 94 + cb;
                float a = acc2[i];
                for (int c = 0; c < cn; ++c) a = fmaf(hv[c], wp[c], a);
                acc2[i] = a;
            }
        }
        #pragma unroll
        for (int i = 0; i < 4; ++i)
            *(float4*)&HT[lane * 68 + ch0 + i * 4] =
                make_float4(acc2[i * 4], acc2[i * 4 + 1], acc2[i * 4 + 2], acc2[i * 4 + 3]);
    }
    __syncthreads();

    // ---- partial pooling over this block's 64 nodes
    if (t < 64) {
        float mx = -3e38f, mn = 3e38f, sm = 0.0f;
        for (int n = 0; n < 64; ++n) {
            float v = HT[n * 68 + t];
            mx = fmaxf(mx, v); mn = fminf(mn, v); sm += v;
        }
        pmax[(size_t)blockIdx.x * 64 + t] = mx;
        pmin[(size_t)blockIdx.x * 64 + t] = mn;
        psum[(size_t)blockIdx.x * 64 + t] = sm;
    }
}

// ---------------------------------------------------------------------------
__global__ void k_pool(const float* __restrict__ pmax, const float* __restrict__ pmin,
                       const float* __restrict__ psum, float* __restrict__ g_out)
{
    const int t = threadIdx.x;
    const int g = blockIdx.x * 4 + (t >> 6);
    const int ch = t & 63;
    const size_t a = (size_t)(2 * g) * 64 + ch, b = a + 64;
    float mx = fmaxf(pmax[a], pmax[b]);
    float mn = fminf(pmin[a], pmin[b]);
    float sm = psum[a] + psum[b];
    float* gp = g_out + (size_t)g * 256;
    gp[ch]        = fmaxf(mx, 0.0f);
    gp[64 + ch]   = fmaxf(mn, 0.0f);
    gp[128 + ch]  = fmaxf(sm, 0.0f);
    gp[192 + ch]  = fmaxf(sm * (1.0f / 128.0f), 0.0f);
}

// ---------------------------------------------------------------------------
__global__ __launch_bounds__(128) void k_gru(
    const float* __restrict__ g, const float* __restrict__ h1_in,
    const float* __restrict__ wih0, const float* __restrict__ whh0,
    const float* __restrict__ bih0, const float* __restrict__ bhh0,
    const float* __restrict__ wih1, const float* __restrict__ whh1,
    const float* __restrict__ bih1, const float* __restrict__ bhh1,
    float* __restrict__ out1, float* __restrict__ hT)
{
    __shared__ float xt[4][256];
    __shared__ float h0[4][32];
    __shared__ float h1l[4][32];
    const int tid = threadIdx.x;
    const int e = tid >> 5;
    const int j = tid & 31;
    const int b = blockIdx.x * 4 + e;

    h0[e][j]  = h1_in[b * 32 + j];
    h1l[e][j] = h1_in[32768 + b * 32 + j];
    __syncthreads();

    for (int t = 0; t < 2; ++t) {
        for (int c = j; c < 256; c += 32)
            xt[e][c] = g[(size_t)(t * 1024 + 4 * c + (b >> 8)) * 256 + (b & 255)];
        __syncthreads();

        float gi0 = bih0[j], gi1 = bih0[32 + j], gi2 = bih0[64 + j];
        for (int c = 0; c < 256; ++c) {
            float xv = xt[e][c];
            gi0 += xv * wih0[j * 256 + c];
            gi1 += xv * wih0[(32 + j) * 256 + c];
            gi2 += xv * wih0[(64 + j) * 256 + c];
        }
        float gh0 = bhh0[j], gh1 = bhh0[32 + j], gh2 = bhh0[64 + j];
        #pragma unroll
        for (int c = 0; c < 32; ++c) {
            float hv = h0[e][c];
            gh0 += hv * whh0[j * 32 + c];
            gh1 += hv * whh0[(32 + j) * 32 + c];
            gh2 += hv * whh0[(64 + j) * 32 + c];
        }
        float r = 1.0f / (1.0f + expf(-(gi0 + gh0)));
        float z = 1.0f / (1.0f + expf(-(gi1 + gh1)));
        float nn = tanhf(gi2 + r * gh2);
        float hn0 = (1.0f - z) * nn + z * h0[e][j];
        __syncthreads();
        h0[e][j] = hn0;
        __syncthreads();

        float ai0 = bih1[j], ai1 = bih1[32 + j], ai2 = bih1[64 + j];
        #pragma unroll
        for (int c = 0; c < 32; ++c) {
            float xv = h0[e][c];
            ai0 += xv * wih1[j * 32 + c];
            ai1 += xv * wih1[(32 + j) * 32 + c];
            ai2 += xv * wih1[(64 + j) * 32 + c];
        }
        float ah0 = bhh1[j], ah1 = bhh1[32 + j], ah2 = bhh1[64 + j];
        #pragma unroll
        for (int c = 0; c < 32; ++c) {
            float hv = h1l[e][c];
            ah0 += hv * whh1[j * 32 + c];
            ah1 += hv * whh1[(32 + j) * 32 + c];
            ah2 += hv * whh1[(64 + j) * 32 + c];
        }
        float r1 = 1.0f / (1.0f + expf(-(ai0 + ah0)));
        float z1 = 1.0f / (1.0f + expf(-(ai1 + ah1)));
        float n1 = tanhf(ai2 + r1 * ah2);
        float hn1 = (1.0f - z1) * n1 + z1 * h1l[e][j];
        __syncthreads();
        h1l[e][j] = hn1;
        out1[(size_t)(t * 1024 + b) * 32 + j] = hn1;
        __syncthreads();
    }
    hT[b * 32 + j]         = h0[e][j];
    hT[32768 + b * 32 + j] = h1l[e][j];
}

__global__ void k_final(const float* __restrict__ out1,
                        const float* __restrict__ nn4W, const float* __restrict__ nn4b,
                        float* __restrict__ y)
{
    const int r = blockIdx.x * 256 + threadIdx.x;
    if (r >= 2048) return;
    const int t = r >> 10, rp = r & 1023;
    const int f = rp >> 5, bb0 = (rp & 31) << 5;
    float acc = nn4b[0];
    #pragma unroll
    for (int c = 0; c < 32; ++c)
        acc += fmaxf(out1[(size_t)(t * 1024 + bb0 + c) * 32 + f], 0.0f) * nn4W[c];
    y[r] = fmaxf(acc, 0.0f);
}

extern "C" void kernel_launch(void* const* d_in, const int* in_sizes, int n_in,
                              void* d_out, int out_size, void* d_ws, size_t ws_size,
                              hipStream_t stream) {
    const float* x    = (const float*)d_in[0];
    const float* h1i  = (const float*)d_in[2];
    const float* W1   = (const float*)d_in[3];
    const float* b1   = (const float*)d_in[4];
    const float* W2   = (const float*)d_in[5];
    const float* b2   = (const float*)d_in[6];
    const float* nn1W = (const float*)d_in[7];
    const float* nn1b = (const float*)d_in[8];
    const float* nn2W = (const float*)d_in[9];
    const float* nn2b = (const float*)d_in[10];
    const float* nn4W = (const float*)d_in[11];
    const float* nn4b = (const float*)d_in[12];
    const float* wih0 = (const float*)d_in[13];
    const float* whh0 = (const float*)d_in[14];
    const float* bih0 = (const float*)d_in[15];
    const float* bhh0 = (const float*)d_in[16];
    const float* wih1 = (const float*)d_in[17];
    const float* whh1 = (const float*)d_in[18];
    const float* bih1 = (const float*)d_in[19];
    const float* bhh1 = (const float*)d_in[20];

    float* ws = (float*)d_ws;
    float* g_buf  = ws;                   // 524288
    float* out1   = g_buf + 524288;       // 65536
    float* W2I    = out1 + 65536;         // 8192
    float* nn2WT  = W2I + 8192;           // 6016
    float* WfT    = nn2WT + 6016;         // 24576 (96x256)
    float* pmax   = WfT + 24576;          // 262144
    float* pmin   = pmax + 262144;        // 262144
    float* psum   = pmin + 262144;        // 262144

    float* y  = (float*)d_out;            // [2048]
    float* hT = y + 2048;                 // [2,1024,32]

    hipLaunchKernelGGL(k_prep, dim3(152), dim3(256), 0, stream,
                       W2, nn2W, nn1W, W2I, nn2WT, WfT);
    hipLaunchKernelGGL(k_edge, dim3(4096), dim3(256), 0, stream,
                       x, W1, b1, W2I, b2, WfT, nn1b, nn2WT, nn2b,
                       pmax, pmin, psum);
    hipLaunchKernelGGL(k_pool, dim3(512), dim3(256), 0, stream,
                       pmax, pmin, psum, g_buf);
    hipLaunchKernelGGL(k_gru, dim3(256), dim3(128), 0, stream,
                       g_buf, h1i, wih0, whh0, bih0, bhh0,
                       wih1, whh1, bih1, bhh1, out1, hT);
    hipLaunchKernelGGL(k_final, dim3(8), dim3(256), 0, stream,
                       out1, nn4W, nn4b, y);
}